// Round 1
// baseline (347.922 us; speedup 1.0000x reference)
//
#include <hip/hip_runtime.h>

// Problem constants
#define B_  8
#define C_  64
#define O_  64
#define H_  80
#define W_  800
#define NCHUNK 13           // ceil(800/64)
#define XT_BYTES 65536000u  // 8*80*800*64*2

typedef short bf16x8 __attribute__((ext_vector_type(8)));
typedef float f32x4  __attribute__((ext_vector_type(4)));

__device__ __forceinline__ unsigned short f2bf(float f) {
    unsigned int u = __float_as_uint(f);
    unsigned int r = u + 0x7FFFu + ((u >> 16) & 1u);   // RNE
    return (unsigned short)(r >> 16);
}

// ---------------------------------------------------------------------------
// Kernel 1: x (B,C,H,W) fp32  ->  xT[b][h][w][c] bf16  (c contiguous)
// Block: 256 thr, one (b,h,64-w chunk). LDS tile [64][65] fp32, pad kills
// write-phase bank conflicts (2-way only, free per m136).
// ---------------------------------------------------------------------------
__global__ void k_transpose(const float* __restrict__ x, unsigned short* __restrict__ xT) {
    __shared__ float tile[64][65];
    const int chunk = blockIdx.x, h = blockIdx.y, b = blockIdx.z;
    const int w0 = chunk * 64;
    const int tid = threadIdx.x;

    const int w = tid & 63, c0 = tid >> 6;      // c0 in 0..3
#pragma unroll
    for (int it = 0; it < 16; ++it) {
        const int c = it * 4 + c0;
        float v = 0.f;
        if (w0 + w < W_) v = x[(((b * C_ + c) * H_ + h) * W_) + w0 + w];
        tile[c][w] = v;                          // banks = (c*65+w)%32 : conflict-free
    }
    __syncthreads();

    const int cp = tid & 31;                     // channel pair 0..31
    const int wr = tid >> 5;                     // 0..7
#pragma unroll
    for (int it = 0; it < 8; ++it) {
        const int ww = it * 8 + wr;
        if (w0 + ww < W_) {
            unsigned int lo = (unsigned int)f2bf(tile[2 * cp][ww]);
            unsigned int hi = (unsigned int)f2bf(tile[2 * cp + 1][ww]);
            ((unsigned int*)xT)[(((b * H_ + h) * W_) + w0 + ww) * 32 + cp] = lo | (hi << 16);
        }
    }
}

// ---------------------------------------------------------------------------
// Kernel 2: pre-swizzle weight (9,O,C) fp32 into exact A-fragment order, bf16.
// elem t = ((kstep*4 + mt)*64 + lane)*8 + j
//   kstep = tap*2+half ; A[m=lane&15][k=(lane>>4)*8+j] ; o=mt*16+m ;
//   c = half*32 + (lane>>4)*8 + j
// ---------------------------------------------------------------------------
__global__ void k_wfrag(const float* __restrict__ wt, unsigned short* __restrict__ wf) {
    const int t = blockIdx.x * 256 + threadIdx.x;   // < 36864
    const int j    = t & 7;
    const int lane = (t >> 3) & 63;
    const int mt   = (t >> 9) & 3;
    const int ks   = t >> 11;                       // 0..17
    const int tap  = ks >> 1, hf = ks & 1;
    const int o = mt * 16 + (lane & 15);
    const int c = hf * 32 + (lane >> 4) * 8 + j;
    wf[t] = f2bf(wt[(tap * 64 + o) * 64 + c]);
}

// ---------------------------------------------------------------------------
// Kernel 3: main fused gather-GEMM.
// Block = 256 thr = 4 independent waves; wave -> (b, h=by*4+wave, 64-w chunk).
// Wave computes all 64 o x 64 px via 4x4 tiles of mfma_f32_16x16x32_bf16,
// K = 9 taps * 64 c, fully unrolled. B-frags gathered straight from xT
// (16B contiguous per lane); A-frags from pre-swizzled wfrag (L2 broadcast).
// ---------------------------------------------------------------------------
__global__ void k_main(const unsigned short* __restrict__ xT,
                       const unsigned short* __restrict__ wfrag,
                       const float* __restrict__ dh, const float* __restrict__ dw,
                       const float* __restrict__ bias, float* __restrict__ out) {
    const int tid  = threadIdx.x;
    const int wave = tid >> 6, lane = tid & 63;
    const int chunk = blockIdx.x;
    const int h = blockIdx.y * 4 + wave;
    const int b = blockIdx.z;
    const int w0 = chunk * 64;
    const int l15 = lane & 15, kq = lane >> 4;

    // Per-pixel gather offsets: 3 row offsets x 3 col offsets (bytes into xT)
    unsigned int ro[4][3], co[4][3];
#pragma unroll
    for (int nt = 0; nt < 4; ++nt) {
        const int pw  = w0 + nt * 16 + l15;
        const int pwc = pw < W_ ? pw : W_ - 1;
        const int dhi = (int)dh[b * W_ + pwc];
        const int dwi = (int)dw[b * W_ + pwc];
        int rD = h - dhi;   if (rD < 0) rD = -rD;            // |h-dh| < H always
        const int rU = (h + dhi < H_) ? (h + dhi) : h;
        int cL = pwc - dwi; if (cL < 0) cL = -cL;
        const int cR = (pwc + dwi < W_) ? (pwc + dwi) : (2 * W_ - 1 - pwc - dwi);
        ro[nt][0] = (unsigned int)(b * H_ + rD) * 102400u;   // *W*C*2
        ro[nt][1] = (unsigned int)(b * H_ + h ) * 102400u;
        ro[nt][2] = (unsigned int)(b * H_ + rU) * 102400u;
        co[nt][0] = (unsigned int)cL  * 128u;                // *C*2
        co[nt][1] = (unsigned int)pwc * 128u;
        co[nt][2] = (unsigned int)cR  * 128u;
    }

    const char* xTb = (const char*)xT;
    const char* wfb = (const char*)wfrag;
    const unsigned int aoff = (unsigned int)lane * 16u;
    const unsigned int boff = (unsigned int)kq * 16u;

    // acc init = bias (C/D layout: col=lane&15 -> pixel, row=(lane>>4)*4+reg -> o)
    f32x4 acc[4][4];
#pragma unroll
    for (int mt = 0; mt < 4; ++mt) {
        const f32x4 bv = *(const f32x4*)(bias + mt * 16 + kq * 4);
#pragma unroll
        for (int nt = 0; nt < 4; ++nt)
#pragma unroll
            for (int r = 0; r < 4; ++r) acc[mt][nt][r] = bv[r];
    }

#pragma unroll
    for (int tap = 0; tap < 9; ++tap) {
        const int i = tap / 3, j = tap % 3;      // row sel, col sel (constants)
#pragma unroll
        for (int hf = 0; hf < 2; ++hf) {
            bf16x8 bfr[4], afr[4];
#pragma unroll
            for (int nt = 0; nt < 4; ++nt)
                bfr[nt] = *(const bf16x8*)(xTb + (ro[nt][i] + co[nt][j]
                                                 + (unsigned int)(hf * 64) + boff));
#pragma unroll
            for (int mt = 0; mt < 4; ++mt)
                afr[mt] = *(const bf16x8*)(wfb
                           + (unsigned int)(((tap * 2 + hf) * 4 + mt) * 1024) + aoff);
#pragma unroll
            for (int mt = 0; mt < 4; ++mt)
#pragma unroll
                for (int nt = 0; nt < 4; ++nt)
                    acc[mt][nt] = __builtin_amdgcn_mfma_f32_16x16x32_bf16(
                        afr[mt], bfr[nt], acc[mt][nt], 0, 0, 0);
        }
    }

    // Epilogue: out[b][o][h][w], o stride = H*W = 64000
#pragma unroll
    for (int mt = 0; mt < 4; ++mt) {
#pragma unroll
        for (int nt = 0; nt < 4; ++nt) {
            const int w = w0 + nt * 16 + l15;
            if (w < W_) {
                const unsigned int ob =
                    ((unsigned int)(b * O_ + mt * 16 + kq * 4) * (unsigned int)H_
                     + (unsigned int)h) * (unsigned int)W_ + (unsigned int)w;
#pragma unroll
                for (int r = 0; r < 4; ++r)
                    out[ob + (unsigned int)r * 64000u] = acc[mt][nt][r];
            }
        }
    }
}

extern "C" void kernel_launch(void* const* d_in, const int* in_sizes, int n_in,
                              void* d_out, int out_size, void* d_ws, size_t ws_size,
                              hipStream_t stream) {
    const float* x      = (const float*)d_in[0];   // (8,64,80,800)
    const float* dh     = (const float*)d_in[1];   // (8,1,800)
    const float* dw     = (const float*)d_in[2];   // (8,1,800)
    const float* weight = (const float*)d_in[3];   // (9,64,64)
    const float* bias   = (const float*)d_in[4];   // (64,)
    float* out = (float*)d_out;

    unsigned short* xT    = (unsigned short*)d_ws;
    unsigned short* wfrag = (unsigned short*)((char*)d_ws + XT_BYTES);

    k_transpose<<<dim3(NCHUNK, H_, B_), 256, 0, stream>>>(x, xT);
    k_wfrag<<<dim3(144), 256, 0, stream>>>(weight, wfrag);
    k_main<<<dim3(NCHUNK, H_ / 4, B_), 256, 0, stream>>>(xT, wfrag, dh, dw, bias, out);
}

// Round 2
// 332.511 us; speedup vs baseline: 1.0463x; 1.0463x over previous
//
#include <hip/hip_runtime.h>

// Problem constants
#define B_  8
#define C_  64
#define O_  64
#define H_  80
#define W_  800
#define NCHUNK 13           // ceil(800/64)
#define XT_BYTES 65536000u  // 8*80*800*64*2

typedef short bf16x8 __attribute__((ext_vector_type(8)));
typedef float f32x4  __attribute__((ext_vector_type(4)));

__device__ __forceinline__ unsigned short f2bf(float f) {
    unsigned int u = __float_as_uint(f);
    unsigned int r = u + 0x7FFFu + ((u >> 16) & 1u);   // RNE
    return (unsigned short)(r >> 16);
}

// ---------------------------------------------------------------------------
// Kernel 1: x (B,C,H,W) fp32 -> xT[b][h][w][c] bf16 (c contiguous).
// Vectorized: float4 loads (1 KB/wave-instr), 2x dwordx4 stores (2 KB/wave).
// LDS tile [64][68]: row stride 68 keeps float4 writes 16B-aligned and the
// b128 write phase hits all 32 banks uniformly (8 phases = minimum).
// Read phase is 4-way bank aliased (1.58x, ~150 cyc/wave) - well under the
// HBM floor for this kernel.
// ---------------------------------------------------------------------------
__global__ void k_transpose(const float* __restrict__ x, unsigned short* __restrict__ xT) {
    __shared__ float tile[64][68];
    const int chunk = blockIdx.x, h = blockIdx.y, b = blockIdx.z;
    const int w0 = chunk * 64;
    const int tid = threadIdx.x;

    // Load phase: lane -> (wf4 = tid&15 float4-granule along w, c = tid>>4 + 16*it)
    const int wf4 = tid & 15;
    const int c0  = tid >> 4;
    const int w   = w0 + wf4 * 4;       // W%4==0 so a float4 is all-valid or all-invalid
#pragma unroll
    for (int it = 0; it < 4; ++it) {
        const int c = it * 16 + c0;
        f32x4 v = {0.f, 0.f, 0.f, 0.f};
        if (w < W_) v = *(const f32x4*)(x + (((b * C_ + c) * H_ + h) * W_) + w);
        *(f32x4*)&tile[c][wf4 * 4] = v;
    }
    __syncthreads();

    // Store phase: px = tid>>2 (0..63), q = tid&3 -> channels q*16..q*16+15 = 8 uints
    const int px = tid >> 2, q = tid & 3;
    if (w0 + px < W_) {
        unsigned int u[8];
#pragma unroll
        for (int i = 0; i < 8; ++i) {
            const int c = q * 16 + 2 * i;
            u[i] = (unsigned int)f2bf(tile[c][px])
                 | ((unsigned int)f2bf(tile[c + 1][px]) << 16);
        }
        unsigned int* dst = (unsigned int*)xT
            + ((size_t)((b * H_ + h) * W_) + w0 + px) * 32 + q * 8;
        *(uint4*)(dst)     = make_uint4(u[0], u[1], u[2], u[3]);
        *(uint4*)(dst + 4) = make_uint4(u[4], u[5], u[6], u[7]);
    }
}

// ---------------------------------------------------------------------------
// Kernel 2: pre-swizzle weight (9,O,C) fp32 into exact A-fragment order, bf16.
// ---------------------------------------------------------------------------
__global__ void k_wfrag(const float* __restrict__ wt, unsigned short* __restrict__ wf) {
    const int t = blockIdx.x * 256 + threadIdx.x;   // < 36864
    const int j    = t & 7;
    const int lane = (t >> 3) & 63;
    const int mt   = (t >> 9) & 3;
    const int ks   = t >> 11;                       // 0..17
    const int tap  = ks >> 1, hf = ks & 1;
    const int o = mt * 16 + (lane & 15);
    const int c = hf * 32 + (lane >> 4) * 8 + j;
    wf[t] = f2bf(wt[(tap * 64 + o) * 64 + c]);
}

// ---------------------------------------------------------------------------
// Kernel 3: main fused gather-GEMM.
// 1D grid, XCD swizzle: b = blockIdx&7 (consecutive blocks round-robin XCDs,
// so each XCD works one batch's 8.2 MB xT slab -> L2-resident gathers).
// Within an XCD, l=blockIdx>>3 sweeps chunk fastest -> ~1 MB row-band locality.
// Distance-1 software prefetch of B/A frags; __launch_bounds__(256,3) gives
// the register room (~170) to keep next-step loads in flight under MFMAs.
// ---------------------------------------------------------------------------
__global__ void __launch_bounds__(256, 3)
k_main(const unsigned short* __restrict__ xT,
       const unsigned short* __restrict__ wfrag,
       const float* __restrict__ dh, const float* __restrict__ dw,
       const float* __restrict__ bias, float* __restrict__ out) {
    const int tid  = threadIdx.x;
    const int wave = tid >> 6, lane = tid & 63;

    const unsigned int flat = blockIdx.x;           // 0..2079
    const int b     = flat & 7;
    const unsigned int l = flat >> 3;               // 0..259
    const int chunk = l % NCHUNK;
    const int by    = l / NCHUNK;                   // 0..19
    const int h  = by * 4 + wave;
    const int w0 = chunk * 64;
    const int l15 = lane & 15, kq = lane >> 4;

    // Per-pixel gather offsets: 3 row offsets x 3 col offsets (bytes into xT)
    unsigned int ro[4][3], co[4][3];
#pragma unroll
    for (int nt = 0; nt < 4; ++nt) {
        const int pw  = w0 + nt * 16 + l15;
        const int pwc = pw < W_ ? pw : W_ - 1;
        const int dhi = (int)dh[b * W_ + pwc];
        const int dwi = (int)dw[b * W_ + pwc];
        int rD = h - dhi;   if (rD < 0) rD = -rD;            // |h-dh| < H always
        const int rU = (h + dhi < H_) ? (h + dhi) : h;
        int cL = pwc - dwi; if (cL < 0) cL = -cL;
        const int cR = (pwc + dwi < W_) ? (pwc + dwi) : (2 * W_ - 1 - pwc - dwi);
        ro[nt][0] = (unsigned int)(b * H_ + rD) * 102400u;   // *W*C*2
        ro[nt][1] = (unsigned int)(b * H_ + h ) * 102400u;
        ro[nt][2] = (unsigned int)(b * H_ + rU) * 102400u;
        co[nt][0] = (unsigned int)cL  * 128u;                // *C*2
        co[nt][1] = (unsigned int)pwc * 128u;
        co[nt][2] = (unsigned int)cR  * 128u;
    }

    const char* xTb = (const char*)xT;
    const char* wfb = (const char*)wfrag;
    const unsigned int aoff = (unsigned int)lane * 16u;
    const unsigned int boff = (unsigned int)kq * 16u;

    // acc init = bias (C/D layout: col=lane&15 -> pixel, row=(lane>>4)*4+reg -> o)
    f32x4 acc[4][4];
#pragma unroll
    for (int mt = 0; mt < 4; ++mt) {
        const f32x4 bv = *(const f32x4*)(bias + mt * 16 + kq * 4);
#pragma unroll
        for (int nt = 0; nt < 4; ++nt)
#pragma unroll
            for (int r = 0; r < 4; ++r) acc[mt][nt][r] = bv[r];
    }

    // K loop: 18 steps (9 taps x 2 c-halves), distance-1 prefetch.
    bf16x8 bcur[4], acur[4], bnxt[4], anxt[4];
#pragma unroll
    for (int nt = 0; nt < 4; ++nt)
        bcur[nt] = *(const bf16x8*)(xTb + (ro[nt][0] + co[nt][0] + boff));
#pragma unroll
    for (int mt = 0; mt < 4; ++mt)
        acur[mt] = *(const bf16x8*)(wfb + (unsigned int)(mt * 1024) + aoff);

#pragma unroll
    for (int s = 0; s < 18; ++s) {
        if (s < 17) {
            const int sn = s + 1;
            const int tap = sn >> 1, hf = sn & 1;
            const int i = tap / 3, j = tap % 3;
#pragma unroll
            for (int nt = 0; nt < 4; ++nt)
                bnxt[nt] = *(const bf16x8*)(xTb + (ro[nt][i] + co[nt][j]
                                                  + (unsigned int)(hf * 64) + boff));
#pragma unroll
            for (int mt = 0; mt < 4; ++mt)
                anxt[mt] = *(const bf16x8*)(wfb
                             + (unsigned int)((sn * 4 + mt) * 1024) + aoff);
        }
#pragma unroll
        for (int mt = 0; mt < 4; ++mt)
#pragma unroll
            for (int nt = 0; nt < 4; ++nt)
                acc[mt][nt] = __builtin_amdgcn_mfma_f32_16x16x32_bf16(
                    acur[mt], bcur[nt], acc[mt][nt], 0, 0, 0);
        if (s < 17) {
#pragma unroll
            for (int nt = 0; nt < 4; ++nt) bcur[nt] = bnxt[nt];
#pragma unroll
            for (int mt = 0; mt < 4; ++mt) acur[mt] = anxt[mt];
        }
    }

    // Epilogue: out[b][o][h][w], o stride = H*W = 64000
#pragma unroll
    for (int mt = 0; mt < 4; ++mt) {
#pragma unroll
        for (int nt = 0; nt < 4; ++nt) {
            const int w = w0 + nt * 16 + l15;
            if (w < W_) {
                const unsigned int ob =
                    ((unsigned int)(b * O_ + mt * 16 + kq * 4) * (unsigned int)H_
                     + (unsigned int)h) * (unsigned int)W_ + (unsigned int)w;
#pragma unroll
                for (int r = 0; r < 4; ++r)
                    out[ob + (unsigned int)r * 64000u] = acc[mt][nt][r];
            }
        }
    }
}

extern "C" void kernel_launch(void* const* d_in, const int* in_sizes, int n_in,
                              void* d_out, int out_size, void* d_ws, size_t ws_size,
                              hipStream_t stream) {
    const float* x      = (const float*)d_in[0];   // (8,64,80,800)
    const float* dh     = (const float*)d_in[1];   // (8,1,800)
    const float* dw     = (const float*)d_in[2];   // (8,1,800)
    const float* weight = (const float*)d_in[3];   // (9,64,64)
    const float* bias   = (const float*)d_in[4];   // (64,)
    float* out = (float*)d_out;

    unsigned short* xT    = (unsigned short*)d_ws;
    unsigned short* wfrag = (unsigned short*)((char*)d_ws + XT_BYTES);

    k_transpose<<<dim3(NCHUNK, H_, B_), 256, 0, stream>>>(x, xT);
    k_wfrag<<<dim3(144), 256, 0, stream>>>(weight, wfrag);
    k_main<<<dim3(NCHUNK * (H_ / 4) * B_), 256, 0, stream>>>(xT, wfrag, dh, dw, bias, out);
}

// Round 3
// 290.690 us; speedup vs baseline: 1.1969x; 1.1439x over previous
//
#include <hip/hip_runtime.h>

// Problem constants
#define B_  8
#define C_  64
#define O_  64
#define H_  80
#define W_  800
#define NCHUNK 13           // ceil(800/64)
#define XT_BYTES 65536000u  // 8*80*800*64*2

#define ROWS_ 8             // staged halo rows: h0-3 .. h0+4
#define ROWB_ 9216          // 72 px * 128 B per staged row
#define LDSX_BYTES (ROWS_ * ROWB_ + 1024)   // +pad for chunk-0 shifted tail

typedef short bf16x8 __attribute__((ext_vector_type(8)));
typedef float f32x4  __attribute__((ext_vector_type(4)));

__device__ __forceinline__ unsigned short f2bf(float f) {
    unsigned int u = __float_as_uint(f);
    unsigned int r = u + 0x7FFFu + ((u >> 16) & 1u);   // RNE
    return (unsigned short)(r >> 16);
}

__device__ __forceinline__ void gld_lds16(const void* g, void* l) {
    __builtin_amdgcn_global_load_lds(
        (const __attribute__((address_space(1))) unsigned int*)g,
        (__attribute__((address_space(3))) unsigned int*)l, 16, 0, 0);
}

// ---------------------------------------------------------------------------
// Kernel 1: x (B,C,H,W) fp32 -> xT bf16, pixel-major with SWIZZLED channel
// groups: 16-B group g (8 ch) of pixel w stored at position (g + w) & 7.
// The swizzle makes k_main's LDS stride-128 ds_read_b128 bank-conflict-free.
// ---------------------------------------------------------------------------
__global__ void k_transpose(const float* __restrict__ x, unsigned short* __restrict__ xT) {
    __shared__ float tile[64][68];
    const int chunk = blockIdx.x, h = blockIdx.y, b = blockIdx.z;
    const int w0 = chunk * 64;
    const int tid = threadIdx.x;

    const int wf4 = tid & 15;
    const int c0  = tid >> 4;
    const int w   = w0 + wf4 * 4;       // W%4==0: float4 all-valid or all-invalid
#pragma unroll
    for (int it = 0; it < 4; ++it) {
        const int c = it * 16 + c0;
        f32x4 v = {0.f, 0.f, 0.f, 0.f};
        if (w < W_) v = *(const f32x4*)(x + (((b * C_ + c) * H_ + h) * W_) + w);
        *(f32x4*)&tile[c][wf4 * 4] = v;
    }
    __syncthreads();

    const int px = tid >> 2, q = tid & 3;
    const int wabs = w0 + px;
    if (wabs < W_) {
        unsigned int u[8];
#pragma unroll
        for (int i = 0; i < 8; ++i) {
            const int c = q * 16 + 2 * i;
            u[i] = (unsigned int)f2bf(tile[c][px])
                 | ((unsigned int)f2bf(tile[c + 1][px]) << 16);
        }
        unsigned int* base = (unsigned int*)xT + ((size_t)((b * H_ + h) * W_) + wabs) * 32;
        const int g0 = (2 * q + wabs) & 7;
        const int g1 = (2 * q + 1 + wabs) & 7;
        *(uint4*)(base + g0 * 4) = make_uint4(u[0], u[1], u[2], u[3]);
        *(uint4*)(base + g1 * 4) = make_uint4(u[4], u[5], u[6], u[7]);
    }
}

// ---------------------------------------------------------------------------
// Kernel 2: pre-swizzle weight (9,O,C) fp32 into exact A-fragment order, bf16.
// ---------------------------------------------------------------------------
__global__ void k_wfrag(const float* __restrict__ wt, unsigned short* __restrict__ wf) {
    const int t = blockIdx.x * 256 + threadIdx.x;   // < 36864
    const int j    = t & 7;
    const int lane = (t >> 3) & 63;
    const int mt   = (t >> 9) & 3;
    const int ks   = t >> 11;                       // 0..17
    const int tap  = ks >> 1, hf = ks & 1;
    const int o = mt * 16 + (lane & 15);
    const int c = hf * 32 + (lane >> 4) * 8 + j;
    wf[t] = f2bf(wt[(tap * 64 + o) * 64 + c]);
}

// ---------------------------------------------------------------------------
// Kernel 3: gather-GEMM with LDS-staged halo.
// Block = 256 thr = 4 waves over (2 h rows) x (2 o-halves); covers 64-px chunk.
// Stage rows h0-3..h0+4, cols w0-3..w0+68 (73.7 KB) via global_load_lds x16
// (pure streaming copies -> latency-insensitive); the data-dependent 9-tap
// gather then runs out of LDS as swizzled conflict-free ds_read_b128.
// 74.8 KB LDS -> 2 blocks/CU; stage/compute phases overlap across blocks.
// ---------------------------------------------------------------------------
__global__ void __launch_bounds__(256, 2)
k_main(const unsigned short* __restrict__ xT,
       const unsigned short* __restrict__ wfrag,
       const float* __restrict__ dh, const float* __restrict__ dw,
       const float* __restrict__ bias, float* __restrict__ out) {
    __shared__ char lx[LDSX_BYTES];
    const int tid  = threadIdx.x;
    const int wave = tid >> 6, lane = tid & 63;

    const unsigned int flat = blockIdx.x;           // 0..4159
    const int b = flat & 7;                         // XCD swizzle: batch per XCD
    const unsigned int l = flat >> 3;               // 0..519
    const int chunk = l % NCHUNK;
    const int hp    = l / NCHUNK;                   // 0..39
    const int h0 = hp * 2;
    const int w0 = chunk * 64;
    const int h   = h0 + (wave & 1);
    const int mtb = (wave >> 1) * 2;                // o-half: mt in {mtb, mtb+1}
    const int l15 = lane & 15, kq = lane >> 4;

    // ---- Stage halo: wave stages row-slots 2*wave, 2*wave+1 ----
    {
        const int col0  = (w0 - 3) < 0 ? 0 : (w0 - 3);
        const int shift = (col0 - (w0 - 3)) * 128;  // 0 or 384 (chunk 0)
#pragma unroll
        for (int k = 0; k < 2; ++k) {
            const int slot = wave * 2 + k;
            int ar = h0 - 3 + slot;
            ar = ar < 0 ? 0 : (ar > H_ - 1 ? H_ - 1 : ar);
            const char* src = (const char*)xT
                + ((size_t)(b * H_ + ar) * W_ + col0) * 128;
            char* dst = lx + slot * ROWB_ + shift;
#pragma unroll
            for (int i = 0; i < 9; ++i)
                gld_lds16(src + i * 1024 + lane * 16, dst + i * 1024);
        }
    }

    // ---- Per-pixel gather addresses (LDS byte offsets) ----
    unsigned int rowb[4][3], colb[4][3];
#pragma unroll
    for (int nt = 0; nt < 4; ++nt) {
        const int pw  = w0 + nt * 16 + l15;
        const int pwc = pw < W_ ? pw : W_ - 1;
        const int dhi = (int)dh[b * W_ + pwc];
        const int dwi = (int)dw[b * W_ + pwc];
        int rD = h - dhi;   if (rD < 0) rD = -rD;
        const int rU = (h + dhi < H_) ? (h + dhi) : h;
        int cL = pwc - dwi; if (cL < 0) cL = -cL;
        const int cR = (pwc + dwi < W_) ? (pwc + dwi) : (2 * W_ - 1 - pwc - dwi);
        rowb[nt][0] = (unsigned int)(rD - h0 + 3) * ROWB_;
        rowb[nt][1] = (unsigned int)(h  - h0 + 3) * ROWB_;
        rowb[nt][2] = (unsigned int)(rU - h0 + 3) * ROWB_;
        const int cs[3] = {cL, pwc, cR};
#pragma unroll
        for (int j = 0; j < 3; ++j)
            colb[nt][j] = (unsigned int)(cs[j] - (w0 - 3)) * 128u
                        + (unsigned int)(((cs[j] + kq) & 7) * 16);
    }

    const char* wfb = (const char*)wfrag;
    const unsigned int aoff = (unsigned int)lane * 16u;

    // acc init = bias
    f32x4 acc[2][4];
#pragma unroll
    for (int mtl = 0; mtl < 2; ++mtl) {
        const f32x4 bv = *(const f32x4*)(bias + (mtb + mtl) * 16 + kq * 4);
#pragma unroll
        for (int nt = 0; nt < 4; ++nt)
#pragma unroll
            for (int r = 0; r < 4; ++r) acc[mtl][nt][r] = bv[r];
    }

    __syncthreads();   // staging complete (compiler drains vmcnt here)

    // ---- K loop: 18 steps; B dist-1 (LDS), A dist-2 (global) prefetch ----
    bf16x8 bcur[4], bnxt[4], a0[2], a1[2], a2[2];
#pragma unroll
    for (int nt = 0; nt < 4; ++nt)
        bcur[nt] = *(const bf16x8*)(lx + rowb[nt][0] + colb[nt][0]);
#pragma unroll
    for (int mtl = 0; mtl < 2; ++mtl) {
        a0[mtl] = *(const bf16x8*)(wfb + (unsigned int)((0 * 4 + mtb + mtl) * 1024) + aoff);
        a1[mtl] = *(const bf16x8*)(wfb + (unsigned int)((1 * 4 + mtb + mtl) * 1024) + aoff);
    }

#pragma unroll
    for (int s = 0; s < 18; ++s) {
        if (s < 17) {
            const int sn = s + 1;
            const int tap = sn >> 1, hf = sn & 1;
            const int i = tap / 3, j = tap % 3;
#pragma unroll
            for (int nt = 0; nt < 4; ++nt) {
                unsigned int a = rowb[nt][i] + colb[nt][j];
                if (hf) a ^= 64u;                  // ch-group +4 under swizzle
                bnxt[nt] = *(const bf16x8*)(lx + a);
            }
        }
        if (s < 16) {
#pragma unroll
            for (int mtl = 0; mtl < 2; ++mtl)
                a2[mtl] = *(const bf16x8*)(wfb
                            + (unsigned int)(((s + 2) * 4 + mtb + mtl) * 1024) + aoff);
        }
#pragma unroll
        for (int mtl = 0; mtl < 2; ++mtl)
#pragma unroll
            for (int nt = 0; nt < 4; ++nt)
                acc[mtl][nt] = __builtin_amdgcn_mfma_f32_16x16x32_bf16(
                    a0[mtl], bcur[nt], acc[mtl][nt], 0, 0, 0);
#pragma unroll
        for (int nt = 0; nt < 4; ++nt) bcur[nt] = bnxt[nt];
#pragma unroll
        for (int mtl = 0; mtl < 2; ++mtl) { a0[mtl] = a1[mtl]; a1[mtl] = a2[mtl]; }
    }

    // ---- Epilogue: out[b][o][h][w] ----
#pragma unroll
    for (int mtl = 0; mtl < 2; ++mtl) {
#pragma unroll
        for (int nt = 0; nt < 4; ++nt) {
            const int w = w0 + nt * 16 + l15;
            if (w < W_) {
                const unsigned int ob =
                    ((unsigned int)(b * O_ + (mtb + mtl) * 16 + kq * 4) * (unsigned int)H_
                     + (unsigned int)h) * (unsigned int)W_ + (unsigned int)w;
#pragma unroll
                for (int r = 0; r < 4; ++r)
                    out[ob + (unsigned int)r * 64000u] = acc[mtl][nt][r];
            }
        }
    }
}

extern "C" void kernel_launch(void* const* d_in, const int* in_sizes, int n_in,
                              void* d_out, int out_size, void* d_ws, size_t ws_size,
                              hipStream_t stream) {
    const float* x      = (const float*)d_in[0];   // (8,64,80,800)
    const float* dh     = (const float*)d_in[1];   // (8,1,800)
    const float* dw     = (const float*)d_in[2];   // (8,1,800)
    const float* weight = (const float*)d_in[3];   // (9,64,64)
    const float* bias   = (const float*)d_in[4];   // (64,)
    float* out = (float*)d_out;

    unsigned short* xT    = (unsigned short*)d_ws;
    unsigned short* wfrag = (unsigned short*)((char*)d_ws + XT_BYTES);

    k_transpose<<<dim3(NCHUNK, H_, B_), 256, 0, stream>>>(x, xT);
    k_wfrag<<<dim3(144), 256, 0, stream>>>(weight, wfrag);
    k_main<<<dim3(NCHUNK * (H_ / 2) * B_), 256, 0, stream>>>(xT, wfrag, dh, dw, bias, out);
}